// Round 18
// baseline (658.188 us; speedup 1.0000x reference)
//
#include <hip/hip_runtime.h>
#include <hip/hip_bf16.h>

typedef __attribute__((ext_vector_type(4))) float f32x4;
typedef __attribute__((ext_vector_type(4))) int   i32x4;
typedef __attribute__((ext_vector_type(8))) short s16x8;
typedef unsigned short ushort_t;

#define MDIM 8192
#define KDIM 4096
#define NDIM 16384
#define NKT  64                 // 64 K-tiles of 64 int8 elems

static __device__ __forceinline__ short f2bf(float f) {
    __bf16 h = (__bf16)f;
    return __builtin_bit_cast(short, h);
}

static __device__ __forceinline__ void gload_lds16(const void* g, void* l) {
    __builtin_amdgcn_global_load_lds(
        (const __attribute__((address_space(1))) unsigned int*)g,
        (__attribute__((address_space(3))) unsigned int*)l,
        16, 0, 0);
}

// ---------------- prep kernels ----------------

// X fp32 -> int8 with per-row symmetric scale (RNE). One block per row.
__global__ __launch_bounds__(256)
void quant_x(const float* __restrict__ X, char* __restrict__ Xq,
             float* __restrict__ sx)
{
    __shared__ float wmax[4];
    const int row = blockIdx.x;
    const float* xr = X + (size_t)row * KDIM;
    const int t = threadIdx.x;
    f32x4 v[4];
    #pragma unroll
    for (int p = 0; p < 4; ++p) v[p] = ((const f32x4*)xr)[t * 4 + p];
    float m = 0.f;
    #pragma unroll
    for (int p = 0; p < 4; ++p)
        #pragma unroll
        for (int q = 0; q < 4; ++q)
            m = fmaxf(m, fabsf(v[p][q]));
    #pragma unroll
    for (int off = 32; off >= 1; off >>= 1)
        m = fmaxf(m, __shfl_xor(m, off));
    if ((t & 63) == 0) wmax[t >> 6] = m;
    __syncthreads();
    m = fmaxf(fmaxf(wmax[0], wmax[1]), fmaxf(wmax[2], wmax[3]));
    const float inv = 127.0f / fmaxf(m, 1e-30f);
    if (t == 0) sx[row] = m * (1.0f / 127.0f);
    int pk[4];
    #pragma unroll
    for (int p = 0; p < 4; ++p) {
        int q0 = min(127, max(-127, __float2int_rn(v[p][0] * inv)));
        int q1 = min(127, max(-127, __float2int_rn(v[p][1] * inv)));
        int q2 = min(127, max(-127, __float2int_rn(v[p][2] * inv)));
        int q3 = min(127, max(-127, __float2int_rn(v[p][3] * inv)));
        pk[p] = (q0 & 255) | ((q1 & 255) << 8) | ((q2 & 255) << 16) | ((q3 & 255) << 24);
    }
    ((i32x4*)(Xq + (size_t)row * KDIM))[t] = *(i32x4*)pk;
}

// W int32 (values in [-127,127]) -> int8 pack, 16 els/thread/iter
__global__ __launch_bounds__(256)
void pack_w(const int* __restrict__ in, char* __restrict__ out, int n16)
{
    for (int i = blockIdx.x * blockDim.x + threadIdx.x; i < n16;
         i += gridDim.x * blockDim.x) {
        int pk[4];
        #pragma unroll
        for (int p = 0; p < 4; ++p) {
            i32x4 a = ((const i32x4*)in)[i * 4 + p];
            pk[p] = (a[0] & 255) | ((a[1] & 255) << 8) |
                    ((a[2] & 255) << 16) | ((a[3] & 255) << 24);
        }
        ((i32x4*)out)[i] = *(i32x4*)pk;
    }
}

// ---- 256x256 int8 GEMM, 4-phase counted-wait schedule (R17 merged 2:1) ----
// R17 (8 phases, 8 MFMA each) hit 45.6% MfmaUtil; per-phase barrier/wait
// overhead (~390 cyc) ~ matches its 326 cyc of MFMA work. R18 merges phase
// pairs: 4 phases/iter (2 K-tiles), 16 MFMA each -> half the barriers per
// MFMA (m201's granularity). Per phase:
//   [ds_reads for NEXT phase][2 gloads] BAR lgkm(N) SB0
//   setprio(1) 16 MFMA setprio(0) [vmcnt(6) at A/C] BAR
// Counted waits (never 0 in-loop); DS FIFO order per wave (R17-validated):
//   lgkm(N): N = own phase's reads -> drains previous phase's reads.
//     A: own 4 (T A4-7)      -> drains D's 8 (T B + A0-3)
//     B: own 8 (T+1 B,A0-3)  -> drains A's 4
//     C: own 4 (T+1 A4-7)    -> drains B's 8
//     D: own 8 (T+2 B,A0-3)  -> drains C's 4
//   vmcnt(6) at A-end: T+1's last staging call is 6 calls back -> drained;
//   BAR publishes for B's reads. At C-end: same for T+2 -> D's reads.
// WAR: w0 = tile T-1's buf, last read prev-C, drained by prev-D's lgkm
// before its trailing BAR; A's gloads issue after it. w1 = r0 (tile T),
// last read phase A, drained by B's lgkm before B's trailing BAR; C's
// gloads issue after it. (Same pattern R17 ran correctly.)
// Levers retained: i8 MFMA (R12), XCD-static A-slab (R13). Byte geometry
// (staging, swizzle, frag offsets) verbatim R12/R17.

#define BAR()   __builtin_amdgcn_s_barrier()
#define SB0()   __builtin_amdgcn_sched_barrier(0)
#define PRIO(N) __builtin_amdgcn_s_setprio(N)
#define LGKM4() do { asm volatile("s_waitcnt lgkmcnt(4)" ::: "memory"); SB0(); } while (0)
#define LGKM8() do { asm volatile("s_waitcnt lgkmcnt(8)" ::: "memory"); SB0(); } while (0)
#define VM6()   asm volatile("s_waitcnt vmcnt(6)" ::: "memory")

#define MM16(M0, PA, PB)                                                       \
    PRIO(1);                                                                   \
    _Pragma("unroll")                                                          \
    for (int mi = 0; mi < 4; ++mi)                                             \
      _Pragma("unroll")                                                        \
      for (int nn = 0; nn < 4; ++nn)                                           \
        acc[(M0) + mi][nn] = __builtin_amdgcn_mfma_i32_16x16x64_i8(            \
            PA[mi], PB[nn], acc[(M0) + mi][nn], 0, 0, 0);                      \
    PRIO(0);

#define ITER4(RB0, RB1, RB2, WB0, WB1, T)                                      \
  {                                                                            \
    const char* r0 = ldsc + (RB0);                                             \
    const char* r1 = ldsc + (RB1);                                             \
    const char* r2 = ldsc + (RB2);                                             \
    char* w0 = ldsc + (WB0);                                                   \
    char* w1 = ldsc + (WB1);                                                   \
    const size_t ko3 = (size_t)(((T) + 3) & (NKT - 1)) * 64;                   \
    const size_t ko4 = (size_t)(((T) + 4) & (NKT - 1)) * 64;                   \
    /* ph A: MFMA acc[0-3] = PAe(T A0-3) x BF(T B); load PAo <- T A4-7 */      \
    PAo[0] = *(const i32x4*)(r0 + aoff[4]);                                    \
    PAo[1] = *(const i32x4*)(r0 + aoff[5]);                                    \
    PAo[2] = *(const i32x4*)(r0 + aoff[6]);                                    \
    PAo[3] = *(const i32x4*)(r0 + aoff[7]);                                    \
    gload_lds16(pA0 + ko3, w0 + 0 + ldsw);                                     \
    gload_lds16(pA1 + ko3, w0 + 8192 + ldsw);                                  \
    BAR(); LGKM4(); MM16(0, PAe, BF); VM6(); BAR();                            \
    /* ph B: MFMA acc[4-7] = PAo x BF; load BG <- T+1 B, PAe <- T+1 A0-3 */    \
    BG[0]  = *(const i32x4*)(r1 + boff[0]);                                    \
    BG[1]  = *(const i32x4*)(r1 + boff[1]);                                    \
    BG[2]  = *(const i32x4*)(r1 + boff[2]);                                    \
    BG[3]  = *(const i32x4*)(r1 + boff[3]);                                    \
    PAe[0] = *(const i32x4*)(r1 + aoff[0]);                                    \
    PAe[1] = *(const i32x4*)(r1 + aoff[1]);                                    \
    PAe[2] = *(const i32x4*)(r1 + aoff[2]);                                    \
    PAe[3] = *(const i32x4*)(r1 + aoff[3]);                                    \
    gload_lds16(pB0 + ko3, w0 + 16384 + ldsw);                                 \
    gload_lds16(pB1 + ko3, w0 + 24576 + ldsw);                                 \
    BAR(); LGKM8(); MM16(4, PAo, BF); BAR();                                   \
    /* ph C: MFMA acc[0-3] = PAe(T+1) x BG; load PAo <- T+1 A4-7 */            \
    PAo[0] = *(const i32x4*)(r1 + aoff[4]);                                    \
    PAo[1] = *(const i32x4*)(r1 + aoff[5]);                                    \
    PAo[2] = *(const i32x4*)(r1 + aoff[6]);                                    \
    PAo[3] = *(const i32x4*)(r1 + aoff[7]);                                    \
    gload_lds16(pA0 + ko4, w1 + 0 + ldsw);                                     \
    gload_lds16(pA1 + ko4, w1 + 8192 + ldsw);                                  \
    BAR(); LGKM4(); MM16(0, PAe, BG); VM6(); BAR();                            \
    /* ph D: MFMA acc[4-7] = PAo x BG; load BF <- T+2 B, PAe <- T+2 A0-3 */    \
    BF[0]  = *(const i32x4*)(r2 + boff[0]);                                    \
    BF[1]  = *(const i32x4*)(r2 + boff[1]);                                    \
    BF[2]  = *(const i32x4*)(r2 + boff[2]);                                    \
    BF[3]  = *(const i32x4*)(r2 + boff[3]);                                    \
    PAe[0] = *(const i32x4*)(r2 + aoff[0]);                                    \
    PAe[1] = *(const i32x4*)(r2 + aoff[1]);                                    \
    PAe[2] = *(const i32x4*)(r2 + aoff[2]);                                    \
    PAe[3] = *(const i32x4*)(r2 + aoff[3]);                                    \
    gload_lds16(pB0 + ko4, w1 + 16384 + ldsw);                                 \
    gload_lds16(pB1 + ko4, w1 + 24576 + ldsw);                                 \
    BAR(); LGKM8(); MM16(4, PAo, BG); BAR();                                   \
  }

__global__ __launch_bounds__(512, 2)
void sl_gemm_i8q(const char* __restrict__ A, const char* __restrict__ Bw,
                 const float* __restrict__ sx,
                 const float* __restrict__ scale_p, const float* __restrict__ bias,
                 float* __restrict__ Out)
{
    __shared__ char ldsbuf[131072];   // ring-4 x (A 16 KB + B 16 KB)
    char* ldsc = ldsbuf;

    const int t    = threadIdx.x;
    const int lane = t & 63;
    const int wave = t >> 6;        // 0..7
    const int wr   = wave >> 2;     // 0..1 : 128 output rows each
    const int wc   = wave & 3;      // 0..3 : 64  output cols each

    // ---- tile mapping (R13): XCD x = bid&7 owns tm in [4x,4x+4)
    //      (A rows [x*1024, x*1024+1024) = 4 MB i8, L2-resident slab)
    int bid = blockIdx.x;                       // 2048 blocks (32 tm x 64 tn)
    int tm = ((bid & 7) << 2) + ((bid >> 3) & 3);
    int tn = bid >> 5;
    const int m0 = tm << 8;
    const int n0 = tn << 8;

    // ---- staging geometry (verbatim R12/R17): thread covers row
    //      (wave*16 + lane>>2) of a 128-row chunk, physical slot lane&3
    const int srow  = wave * 16 + (lane >> 2);            // 0..127
    const int sslot = lane & 3;
    const int sA    = sslot ^ ((srow >> 1) & 3);          // logical slot
    const char* pA0 = A  + (size_t)(m0 + srow) * KDIM + sA * 16;
    const char* pA1 = pA0 + (size_t)128 * KDIM;
    const char* pB0 = Bw + (size_t)(n0 + srow) * KDIM + sA * 16;
    const char* pB1 = pB0 + (size_t)128 * KDIM;
    const int ldsw = wave * 1024;                          // wave-uniform dest

    // ---- fragment read offsets (byte, buf-relative; verbatim R12/R17)
    const int fr = lane & 15;
    const int fs = lane >> 4;                              // 0..3
    int aoff[8], boff[4];
    #pragma unroll
    for (int i = 0; i < 8; ++i) {
        int ra = wr * 128 + i * 16 + fr;
        aoff[i] = ra * 64 + ((fs ^ ((ra >> 1) & 3)) * 16);
    }
    #pragma unroll
    for (int j = 0; j < 4; ++j) {
        int rb = wc * 64 + j * 16 + fr;
        boff[j] = 16384 + rb * 64 + ((fs ^ ((rb >> 1) & 3)) * 16);
    }

    i32x4 acc[8][4];
    #pragma unroll
    for (int i = 0; i < 8; ++i)
        #pragma unroll
        for (int j = 0; j < 4; ++j)
            acc[i][j] = (i32x4){0, 0, 0, 0};

    i32x4 PAe[4], PAo[4], BF[4], BG[4];

    // ---- prologue: stage tiles 0,1,2 -> bufs 0,1,2
    #pragma unroll
    for (int kt = 0; kt < 3; ++kt) {
        const size_t ko = (size_t)kt * 64;
        char* b = ldsc + kt * 32768;
        gload_lds16(pA0 + ko, b + ldsw);
        gload_lds16(pA1 + ko, b + 8192  + ldsw);
        gload_lds16(pB0 + ko, b + 16384 + ldsw);
        gload_lds16(pB1 + ko, b + 24576 + ldsw);
    }
    asm volatile("s_waitcnt vmcnt(8)" ::: "memory");   // tile 0 landed
    BAR();
    SB0();

    // preload tile 0: BF <- B0-3, PAe <- A0-3 (8 reads; ph A's lgkm(4)
    // drains them before the first MFMA)
    BF[0]  = *(const i32x4*)(ldsc + boff[0]);
    BF[1]  = *(const i32x4*)(ldsc + boff[1]);
    BF[2]  = *(const i32x4*)(ldsc + boff[2]);
    BF[3]  = *(const i32x4*)(ldsc + boff[3]);
    PAe[0] = *(const i32x4*)(ldsc + aoff[0]);
    PAe[1] = *(const i32x4*)(ldsc + aoff[1]);
    PAe[2] = *(const i32x4*)(ldsc + aoff[2]);
    PAe[3] = *(const i32x4*)(ldsc + aoff[3]);

    // ring: iter even {r0,r1,r2,w0,w1}={0,1,2,3,0}; odd {2,3,0,1,2} (x32768)
    for (int tt = 0; tt < NKT; tt += 4) {
        ITER4(0 * 32768, 1 * 32768, 2 * 32768, 3 * 32768, 0 * 32768, tt);
        ITER4(2 * 32768, 3 * 32768, 0 * 32768, 1 * 32768, 2 * 32768, tt + 2);
    }

    // ---- epilogue: D col = lane&15, row = fs*4 + q; per-row dequant + bias
    const float scale = scale_p[0];
    #pragma unroll
    for (int i = 0; i < 8; ++i) {
        const int r0 = m0 + wr * 128 + i * 16 + fs * 4;
        float s4[4];
        #pragma unroll
        for (int q = 0; q < 4; ++q) s4[q] = sx[r0 + q] * scale;
        #pragma unroll
        for (int j = 0; j < 4; ++j) {
            const int c   = n0 + wc * 64 + j * 16 + fr;
            const float bj = bias[c];
            float* op = Out + (size_t)r0 * NDIM + c;
            #pragma unroll
            for (int q = 0; q < 4; ++q)
                op[(size_t)q * NDIM] = (float)acc[i][j][q] * s4[q] + bj;
        }
    }
}

// ---------------- fallback (fp32 direct, no workspace) ----------------

__global__ __launch_bounds__(256, 2)
void sl_gemm_fb(const float* __restrict__ X, const int* __restrict__ Wq,
                const float* __restrict__ scale_p, const float* __restrict__ bias,
                float* __restrict__ Out)
{
    __shared__ s16x8 As[128 * 4];
    __shared__ s16x8 Bs[128 * 4];

    const int t    = threadIdx.x;
    const int lane = t & 63;
    const int wave = t >> 6;
    const int wr   = wave >> 1;
    const int wc   = wave & 1;

    int bid = blockIdx.x;
    int swz = (bid & 7) * 1024 + (bid >> 3);
    int panel   = swz >> 10;
    int inpanel = swz & 1023;
    int tn = (panel << 4) + (inpanel >> 6);
    int tm = inpanel & 63;
    const int m0 = tm << 7;
    const int n0 = tn << 7;

    const int srow  = t >> 1;
    const int shalf = t & 1;
    const float* Xp = X  + (size_t)(m0 + srow) * KDIM + shalf * 16;
    const int*   Wp = Wq + (size_t)(n0 + srow) * KDIM + shalf * 16;

    f32x4 acc[4][4];
    #pragma unroll
    for (int i = 0; i < 4; ++i)
        #pragma unroll
        for (int j = 0; j < 4; ++j)
            acc[i][j] = (f32x4){0.f, 0.f, 0.f, 0.f};

    const int fr = lane & 15;
    const int fs = lane >> 4;

    f32x4 ar[4];
    i32x4 br[4];
    #pragma unroll
    for (int p = 0; p < 4; ++p) {
        ar[p] = *(const f32x4*)(Xp + p * 4);
        br[p] = *(const i32x4*)(Wp + p * 4);
    }

    const int wbase = srow * 4;
    const int wswz  = (srow >> 1) & 3;
    const int ws0   = (shalf * 2)     ^ wswz;
    const int ws1   = (shalf * 2 + 1) ^ wswz;

    for (int kt = 0; kt < KDIM / 32; ++kt) {
        __syncthreads();
        {
            s16x8 v0, v1;
            #pragma unroll
            for (int q = 0; q < 8; ++q) v0[q] = f2bf(ar[q >> 2][q & 3]);
            #pragma unroll
            for (int q = 0; q < 8; ++q) v1[q] = f2bf(ar[2 + (q >> 2)][q & 3]);
            As[wbase + ws0] = v0;
            As[wbase + ws1] = v1;
            s16x8 u0, u1;
            #pragma unroll
            for (int q = 0; q < 8; ++q) u0[q] = f2bf((float)br[q >> 2][q & 3]);
            #pragma unroll
            for (int q = 0; q < 8; ++q) u1[q] = f2bf((float)br[2 + (q >> 2)][q & 3]);
            Bs[wbase + ws0] = u0;
            Bs[wbase + ws1] = u1;
        }
        __syncthreads();

        if (kt + 1 < KDIM / 32) {
            const float* Xn = Xp + (size_t)(kt + 1) * 32;
            const int*   Wn = Wp + (size_t)(kt + 1) * 32;
            #pragma unroll
            for (int p = 0; p < 4; ++p) {
                ar[p] = *(const f32x4*)(Xn + p * 4);
                br[p] = *(const i32x4*)(Wn + p * 4);
            }
        }

        s16x8 af[4], bq[4];
        #pragma unroll
        for (int i = 0; i < 4; ++i) {
            int row = wr * 64 + i * 16 + fr;
            af[i] = As[row * 4 + (fs ^ ((row >> 1) & 3))];
        }
        #pragma unroll
        for (int j = 0; j < 4; ++j) {
            int col = wc * 64 + j * 16 + fr;
            bq[j] = Bs[col * 4 + (fs ^ ((col >> 1) & 3))];
        }
        #pragma unroll
        for (int i = 0; i < 4; ++i)
            #pragma unroll
            for (int j = 0; j < 4; ++j)
                acc[i][j] = __builtin_amdgcn_mfma_f32_16x16x32_bf16(
                    af[i], bq[j], acc[i][j], 0, 0, 0);
    }

    const float scale = scale_p[0];
    #pragma unroll
    for (int j = 0; j < 4; ++j) {
        const int c  = n0 + wc * 64 + j * 16 + fr;
        const float bj = bias[c];
        #pragma unroll
        for (int i = 0; i < 4; ++i) {
            const int r0 = m0 + wr * 64 + i * 16 + fs * 4;
            float* op = Out + (size_t)r0 * NDIM + c;
            #pragma unroll
            for (int q = 0; q < 4; ++q)
                op[(size_t)q * NDIM] = acc[i][j][q] * scale + bj;
        }
    }
}

extern "C" void kernel_launch(void* const* d_in, const int* in_sizes, int n_in,
                              void* d_out, int out_size, void* d_ws, size_t ws_size,
                              hipStream_t stream) {
    const float* X     = (const float*)d_in[0];
    const int*   Wq    = (const int*)d_in[1];   // int8 widened to int32 by harness
    const float* scale = (const float*)d_in[2];
    const float* bias  = (const float*)d_in[3];
    float*       Out   = (float*)d_out;

    const size_t xqB = (size_t)MDIM * KDIM;          // 33.5 MB
    const size_t wqB = (size_t)NDIM * KDIM;          // 67 MB
    const size_t sxB = (size_t)MDIM * sizeof(float); // 32 KB
    if (ws_size >= xqB + wqB + sxB) {
        char*  Xq  = (char*)d_ws;
        char*  Wq8 = (char*)d_ws + xqB;
        float* sx  = (float*)((char*)d_ws + xqB + wqB);
        hipLaunchKernelGGL(quant_x, dim3(MDIM), dim3(256), 0, stream, X, Xq, sx);
        hipLaunchKernelGGL(pack_w, dim3(2048), dim3(256), 0, stream,
                           Wq, Wq8, NDIM * KDIM / 16);
        hipLaunchKernelGGL(sl_gemm_i8q, dim3(2048), dim3(512), 0, stream,
                           Xq, Wq8, sx, scale, bias, Out);
    } else {
        hipLaunchKernelGGL(sl_gemm_fb, dim3(8192), dim3(256), 0, stream,
                           X, Wq, scale, bias, Out);
    }
}